// Round 5
// baseline (109.027 us; speedup 1.0000x reference)
//
#include <hip/hip_runtime.h>
#include <hip/hip_bf16.h>
#include <math.h>

#define SEQ   2048
#define DIM   512
#define NH    8
#define DH    64
#define LR    7
#define TI    8
#define NROW  (TI + 2 * LR)   // 22

typedef __bf16 bf16_t;
typedef __bf16 bf16x8 __attribute__((ext_vector_type(8)));
typedef float  f32x4  __attribute__((ext_vector_type(4)));

typedef __attribute__((address_space(3))) void  lds_void;
typedef __attribute__((address_space(1))) const void gbl_cvoid;

// ---------------------------------------------------------------------------
// Kernel 0 (prep): blocks [0,1024): hsb = bf16(hs)
//                  blocks [1024,1152): Wt[n][k] = bf16(W[k][n])
// ---------------------------------------------------------------------------
__global__ __launch_bounds__(256) void prep(
    const float* __restrict__ hs,
    const float* __restrict__ Wq, const float* __restrict__ Wk,
    bf16_t* __restrict__ hsb,            // [4096][512]
    bf16_t* __restrict__ Wt)             // [1024][512]
{
    const int tid = threadIdx.x;
    const int bx  = blockIdx.x;

    if (bx < 1024) {
        const size_t base = ((size_t)bx * 256 + tid) * 8;
        const float4 f0 = *(const float4*)(hs + base);
        const float4 f1 = *(const float4*)(hs + base + 4);
        union { bf16_t b[8]; uint4 u; } cv;
        cv.b[0]=(bf16_t)f0.x; cv.b[1]=(bf16_t)f0.y; cv.b[2]=(bf16_t)f0.z; cv.b[3]=(bf16_t)f0.w;
        cv.b[4]=(bf16_t)f1.x; cv.b[5]=(bf16_t)f1.y; cv.b[6]=(bf16_t)f1.z; cv.b[7]=(bf16_t)f1.w;
        *(uint4*)(hsb + base) = cv.u;
        return;
    }

    __shared__ float tile[64][68];
    const int t  = bx - 1024;
    const int k0 = (t & 7) * 64;
    const int n0 = (t >> 3) * 64;
    const float* W = (n0 < DIM) ? Wq : Wk;
    const int nn0 = n0 & (DIM - 1);

    #pragma unroll
    for (int ph = 0; ph < 4; ++ph) {
        const int kk = ph * 16 + (tid >> 4);
        const int nn = (tid & 15) * 4;
        const float4 v = *(const float4*)(W + (size_t)(k0 + kk) * DIM + nn0 + nn);
        tile[kk][nn + 0] = v.x; tile[kk][nn + 1] = v.y;
        tile[kk][nn + 2] = v.z; tile[kk][nn + 3] = v.w;
    }
    __syncthreads();
    #pragma unroll
    for (int ph = 0; ph < 4; ++ph) {
        const int nn = ph * 16 + (tid >> 4);
        const int kk = (tid & 15) * 4;
        union { bf16_t b[4]; ushort4 u; } cv;
        #pragma unroll
        for (int u = 0; u < 4; ++u) cv.b[u] = (bf16_t)tile[kk + u][nn];
        *(ushort4*)(Wt + (size_t)(n0 + nn) * DIM + k0 + kk) = cv.u;
    }
}

// ---------------------------------------------------------------------------
// Kernel 1: qkb[4096][1024] = hsb @ Wt^T.  Full-K restructure:
// 128x128 tile, BK=128 -> only 4 K-iters (4 barriers).  64 KB LDS.
// XOR swizzle: LDS[row][c'] = global chunk (c' ^ (row&15)); frag read uses
// chunk (s*4+quad)^l15 -> all 8 bank groups covered (b128-optimal).
// Epilogue: acc -> LDS (bf16) -> 256B-coalesced uint4 stores.
// ---------------------------------------------------------------------------
__global__ __launch_bounds__(256) void qk_gemm_v5(
    const bf16_t* __restrict__ A,    // [4096][512]
    const bf16_t* __restrict__ Bt,   // [1024][512]
    bf16_t* __restrict__ C)          // [4096][1024]
{
    __shared__ bf16_t As[128 * 128];   // 32 KB
    __shared__ bf16_t Bs[128 * 128];   // 32 KB

    const int tid  = threadIdx.x;
    const int wave = tid >> 6;
    const int lane = tid & 63;
    const int l15  = lane & 15;
    const int quad = lane >> 4;
    const int wm   = (wave >> 1) * 64;
    const int wn_  = (wave & 1) * 64;
    const int m0   = blockIdx.x * 128;
    const int n0   = blockIdx.y * 128;

    f32x4 acc[4][4] = {};

    for (int kt = 0; kt < 4; ++kt) {
        const int k0 = kt * 128;
        #pragma unroll
        for (int g = 0; g < 8; ++g) {
            const int ra = wave * 32 + g * 4 + quad;       // LDS row this lane feeds
            const int cg = (l15 ^ (ra & 15)) * 8;          // swizzled global chunk
            __builtin_amdgcn_global_load_lds(
                (gbl_cvoid*)(A + (size_t)(m0 + ra) * DIM + k0 + cg),
                (lds_void*)(As + (wave * 32 + g * 4) * 128), 16, 0, 0);
            __builtin_amdgcn_global_load_lds(
                (gbl_cvoid*)(Bt + (size_t)(n0 + ra) * DIM + k0 + cg),
                (lds_void*)(Bs + (wave * 32 + g * 4) * 128), 16, 0, 0);
        }
        __syncthreads();

        #pragma unroll
        for (int s = 0; s < 4; ++s) {
            const int cs = ((s * 4 + quad) ^ l15) * 8;
            bf16x8 af[4], bfv[4];
            #pragma unroll
            for (int mi = 0; mi < 4; ++mi)
                af[mi] = *(const bf16x8*)(As + (wm + mi * 16 + l15) * 128 + cs);
            #pragma unroll
            for (int ni = 0; ni < 4; ++ni)
                bfv[ni] = *(const bf16x8*)(Bs + (wn_ + ni * 16 + l15) * 128 + cs);
            #pragma unroll
            for (int mi = 0; mi < 4; ++mi)
                #pragma unroll
                for (int ni = 0; ni < 4; ++ni)
                    acc[mi][ni] = __builtin_amdgcn_mfma_f32_16x16x32_bf16(
                        af[mi], bfv[ni], acc[mi][ni], 0, 0, 0);
        }
        __syncthreads();
    }

    // ---- epilogue: repack through LDS for coalesced bf16 stores ----
    bf16_t* Ct = As;
    #pragma unroll
    for (int mi = 0; mi < 4; ++mi)
        #pragma unroll
        for (int ni = 0; ni < 4; ++ni)
            #pragma unroll
            for (int r = 0; r < 4; ++r)
                Ct[(wm + mi * 16 + quad * 4 + r) * 128 + wn_ + ni * 16 + l15] =
                    (bf16_t)acc[mi][ni][r];
    __syncthreads();
    #pragma unroll
    for (int i = 0; i < 8; ++i) {
        const int idx = i * 256 + tid;       // 0..2047
        const int row = idx >> 4;
        const int c16 = idx & 15;
        *(uint4*)(C + (size_t)(m0 + row) * 1024 + n0 + c16 * 8) =
            *(const uint4*)(Ct + row * 128 + c16 * 8);
    }
}

// ---------------------------------------------------------------------------
// Kernel 2: scores + softmax -> normalized weights wn_g[B*256][64][16].
// TI=8 i-tile per block, all heads.  Q/K staged bf16 via glds with +8 row
// padding (stride 520) -> conflict-free MFMA frag reads.
// ---------------------------------------------------------------------------
#define QS 520

__global__ __launch_bounds__(256) void scores_k(
    const bf16_t* __restrict__ qkb,   // [4096][1024]  (q | k)
    float* __restrict__ wn_g)         // [B*256][64][16]
{
    __shared__ bf16_t Qb[16 * QS];    // 16.3 KB (rows 8-15 garbage, masked)
    __shared__ bf16_t Kb[32 * QS];    // 33.3 KB (rows 22-31 garbage, masked)
    __shared__ float sw2[NH][TI][24];

    const int tid  = threadIdx.x;
    const int wave = tid >> 6;
    const int lane = tid & 63;
    const int l15  = lane & 15;
    const int quad = lane >> 4;
    const int i0   = blockIdx.x * TI;
    const int b    = blockIdx.y;

    for (int r = wave; r < TI; r += 4) {
        const bf16_t* g = qkb + (size_t)(b * SEQ + i0 + r) * 1024 + lane * 8;
        __builtin_amdgcn_global_load_lds((gbl_cvoid*)g, (lds_void*)(Qb + r * QS), 16, 0, 0);
    }
    for (int r = wave; r < NROW; r += 4) {
        int jg = i0 - LR + r;
        jg = jg < 0 ? 0 : (jg > SEQ - 1 ? SEQ - 1 : jg);
        const bf16_t* g = qkb + (size_t)(b * SEQ + jg) * 1024 + DIM + lane * 8;
        __builtin_amdgcn_global_load_lds((gbl_cvoid*)g, (lds_void*)(Kb + r * QS), 16, 0, 0);
    }
    __syncthreads();

    #pragma unroll
    for (int hh = 0; hh < 2; ++hh) {
        const int h = wave * 2 + hh;
        f32x4 sacc[2] = {};
        #pragma unroll
        for (int s = 0; s < 2; ++s) {
            const bf16x8 aq = *(const bf16x8*)(Qb + l15 * QS + h * DH + s * 32 + quad * 8);
            #pragma unroll
            for (int t = 0; t < 2; ++t) {
                const bf16x8 bk = *(const bf16x8*)(Kb + (t * 16 + l15) * QS + h * DH + s * 32 + quad * 8);
                sacc[t] = __builtin_amdgcn_mfma_f32_16x16x32_bf16(aq, bk, sacc[t], 0, 0, 0);
            }
        }
        #pragma unroll
        for (int t = 0; t < 2; ++t) {
            const int jj = t * 16 + l15;
            if (jj < NROW) {
                #pragma unroll
                for (int r = 0; r < 4; ++r) {
                    const int ii = quad * 4 + r;
                    if (ii < TI) sw2[h][ii][jj] = sacc[t][r] * 0.125f;
                }
            }
        }
    }
    __syncthreads();

    if (tid < NH * TI) {
        const int h  = tid >> 3;
        const int ii = tid & (TI - 1);
        const int i  = i0 + ii;
        float v[16], m = -1e30f;
        #pragma unroll
        for (int t = 0; t < 15; ++t) {
            const int jg = i - LR + t;
            v[t] = (jg >= 0 && jg < SEQ) ? sw2[h][ii][ii + t] : -1e30f;
            m = fmaxf(m, v[t]);
        }
        float sum = 0.f;
        #pragma unroll
        for (int t = 0; t < 15; ++t) { v[t] = __expf(v[t] - m); sum += v[t]; }
        const float inv = 1.f / sum;
        #pragma unroll
        for (int t = 0; t < 15; ++t) v[t] *= inv;
        v[15] = 0.f;
        float* dst = wn_g + ((size_t)(b * 256 + blockIdx.x) * 64 + tid) * 16;
        #pragma unroll
        for (int u = 0; u < 4; ++u)
            *(float4*)(dst + u * 4) = make_float4(v[u*4], v[u*4+1], v[u*4+2], v[u*4+3]);
    }
}

// ---------------------------------------------------------------------------
// Kernel 3: context.  Block = (i-tile, d-half, b).  27 KB LDS -> ~5 blk/CU.
// One sync; band rows padded to stride 260 -> conflict-free P5 reads.
// ---------------------------------------------------------------------------
#define BST 260

__global__ __launch_bounds__(256) void context_k(
    const float* __restrict__ hs,     // [B,SEQ,DIM] fp32
    const float* __restrict__ wn_g,   // [B*256][64][16]
    float* __restrict__ out)          // [B,NH,SEQ,DIM]
{
    __shared__ float band[NROW * BST];   // 22.9 KB
    __shared__ float wnl[64 * 16];       // 4 KB

    const int tid  = threadIdx.x;
    const int wave = tid >> 6;
    const int lane = tid & 63;
    const int tile = blockIdx.x;
    const int dh_  = blockIdx.y;         // d-half (0/1)
    const int b    = blockIdx.z;
    const int i0   = tile * TI;

    for (int r = wave; r < NROW; r += 4) {
        int jg = i0 - LR + r;
        jg = jg < 0 ? 0 : (jg > SEQ - 1 ? SEQ - 1 : jg);
        const float* g = hs + ((size_t)b * SEQ + jg) * DIM + dh_ * 256 + lane * 4;
        __builtin_amdgcn_global_load_lds((gbl_cvoid*)g, (lds_void*)(band + r * BST), 16, 0, 0);
    }
    {
        const float* g = wn_g + (size_t)(b * 256 + tile) * 1024 + wave * 256 + lane * 4;
        __builtin_amdgcn_global_load_lds((gbl_cvoid*)g, (lds_void*)(wnl + wave * 256), 16, 0, 0);
    }
    __syncthreads();

    const int h  = tid >> 5;             // 0..7
    const int iq = (tid >> 4) & 1;       // 0..1
    const int dg = tid & 15;             // 0..15

    float wreg[4][15];
    #pragma unroll
    for (int t = 0; t < 4; ++t) {
        const int pair = h * TI + iq * 4 + t;
        #pragma unroll
        for (int j = 0; j < 15; ++j) wreg[t][j] = wnl[pair * 16 + j];
    }

    const int r0 = iq * 4;
    float* op = out + ((size_t)(b * NH + h) * SEQ + i0 + iq * 4) * DIM + dh_ * 256;

    for (int c = 0; c < 4; ++c) {        // 4 chunks of 64 cols (256 total)
        const int dbase = c * 64 + dg * 4;
        float4 a0 = {0,0,0,0}, a1 = {0,0,0,0}, a2 = {0,0,0,0}, a3 = {0,0,0,0};
        #pragma unroll
        for (int rr = 0; rr < 18; ++rr) {
            const float4 v = *(const float4*)&band[(r0 + rr) * BST + dbase];
            if (rr <= 14) {
                const float w = wreg[0][rr];
                a0.x += w * v.x; a0.y += w * v.y; a0.z += w * v.z; a0.w += w * v.w;
            }
            if (rr >= 1 && rr <= 15) {
                const float w = wreg[1][rr - 1];
                a1.x += w * v.x; a1.y += w * v.y; a1.z += w * v.z; a1.w += w * v.w;
            }
            if (rr >= 2 && rr <= 16) {
                const float w = wreg[2][rr - 2];
                a2.x += w * v.x; a2.y += w * v.y; a2.z += w * v.z; a2.w += w * v.w;
            }
            if (rr >= 3) {
                const float w = wreg[3][rr - 3];
                a3.x += w * v.x; a3.y += w * v.y; a3.z += w * v.z; a3.w += w * v.w;
            }
        }
        *(float4*)(op + (size_t)0 * DIM + dbase) = a0;
        *(float4*)(op + (size_t)1 * DIM + dbase) = a1;
        *(float4*)(op + (size_t)2 * DIM + dbase) = a2;
        *(float4*)(op + (size_t)3 * DIM + dbase) = a3;
    }
}

// ---------------------------------------------------------------------------
extern "C" void kernel_launch(void* const* d_in, const int* in_sizes, int n_in,
                              void* d_out, int out_size, void* d_ws, size_t ws_size,
                              hipStream_t stream)
{
    const float* hs = (const float*)d_in[0];
    const float* Wq = (const float*)d_in[1];
    const float* Wk = (const float*)d_in[2];
    float* out = (float*)d_out;

    const int B = in_sizes[0] / (SEQ * DIM);   // 2
    const int M = B * SEQ;                     // 4096

    bf16_t* hsb  = (bf16_t*)d_ws;                          // 4 MB
    bf16_t* Wt   = (bf16_t*)((char*)d_ws + (4 << 20));     // 1 MB
    bf16_t* qkb  = (bf16_t*)((char*)d_ws + (5 << 20));     // 8 MB
    float*  wn_g = (float*)((char*)d_ws + (13 << 20));     // 2 MB

    prep<<<1024 + 128, 256, 0, stream>>>(hs, Wq, Wk, hsb, Wt);
    qk_gemm_v5<<<dim3(M / 128, 1024 / 128), 256, 0, stream>>>(hsb, Wt, qkb);
    scores_k<<<dim3(SEQ / TI, B), 256, 0, stream>>>(qkb, wn_g);
    context_k<<<dim3(SEQ / TI, 2, B), 256, 0, stream>>>(hs, wn_g, out);
}

// Round 6
// 107.655 us; speedup vs baseline: 1.0127x; 1.0127x over previous
//
#include <hip/hip_runtime.h>
#include <hip/hip_bf16.h>
#include <math.h>

#define SEQ   2048
#define DIM   512
#define NH    8
#define DH    64
#define LR    7
#define TI    8
#define NROW  (TI + 2 * LR)   // 22

typedef __bf16 bf16_t;
typedef __bf16 bf16x8 __attribute__((ext_vector_type(8)));
typedef float  f32x4  __attribute__((ext_vector_type(4)));

typedef __attribute__((address_space(3))) void  lds_void;
typedef __attribute__((address_space(1))) const void gbl_cvoid;

// ---------------------------------------------------------------------------
// Kernel 0 (prep): blocks [0,1024): hsb = bf16(hs)
//                  blocks [1024,1152): Wt[n][k] = bf16(W[k][n])
// ---------------------------------------------------------------------------
__global__ __launch_bounds__(256) void prep(
    const float* __restrict__ hs,
    const float* __restrict__ Wq, const float* __restrict__ Wk,
    bf16_t* __restrict__ hsb,            // [4096][512]
    bf16_t* __restrict__ Wt)             // [1024][512]
{
    const int tid = threadIdx.x;
    const int bx  = blockIdx.x;

    if (bx < 1024) {
        const size_t base = ((size_t)bx * 256 + tid) * 8;
        const float4 f0 = *(const float4*)(hs + base);
        const float4 f1 = *(const float4*)(hs + base + 4);
        union { bf16_t b[8]; uint4 u; } cv;
        cv.b[0]=(bf16_t)f0.x; cv.b[1]=(bf16_t)f0.y; cv.b[2]=(bf16_t)f0.z; cv.b[3]=(bf16_t)f0.w;
        cv.b[4]=(bf16_t)f1.x; cv.b[5]=(bf16_t)f1.y; cv.b[6]=(bf16_t)f1.z; cv.b[7]=(bf16_t)f1.w;
        *(uint4*)(hsb + base) = cv.u;
        return;
    }

    __shared__ float tile[64][68];
    const int t  = bx - 1024;
    const int k0 = (t & 7) * 64;
    const int n0 = (t >> 3) * 64;
    const float* W = (n0 < DIM) ? Wq : Wk;
    const int nn0 = n0 & (DIM - 1);

    #pragma unroll
    for (int ph = 0; ph < 4; ++ph) {
        const int kk = ph * 16 + (tid >> 4);
        const int nn = (tid & 15) * 4;
        const float4 v = *(const float4*)(W + (size_t)(k0 + kk) * DIM + nn0 + nn);
        tile[kk][nn + 0] = v.x; tile[kk][nn + 1] = v.y;
        tile[kk][nn + 2] = v.z; tile[kk][nn + 3] = v.w;
    }
    __syncthreads();
    #pragma unroll
    for (int ph = 0; ph < 4; ++ph) {
        const int nn = ph * 16 + (tid >> 4);
        const int kk = (tid & 15) * 4;
        union { bf16_t b[4]; ushort4 u; } cv;
        #pragma unroll
        for (int u = 0; u < 4; ++u) cv.b[u] = (bf16_t)tile[kk + u][nn];
        *(ushort4*)(Wt + (size_t)(n0 + nn) * DIM + k0 + kk) = cv.u;
    }
}

// ---------------------------------------------------------------------------
// Kernel 1 (v6): qkb[4096][1024] = hsb @ Wt^T.
// Occupancy-first: 64x64 tile, BK=64 (twin 32-wide panels, proven R4/m97
// glds layout), 1D grid of 1024 blocks = 4 blocks/CU (whole grid resident).
// m = bid&63 so the 16 blocks sharing an A-panel are id-congruent mod 8
// -> same XCD L2.  4 waves, each 32x32 (2x2 MFMA accs).  16 KB LDS.
// Epilogue repacks via LDS for uint4 stores.
// ---------------------------------------------------------------------------
__global__ __launch_bounds__(256) void qk_gemm_v6(
    const bf16_t* __restrict__ A,    // [4096][512]
    const bf16_t* __restrict__ Bt,   // [1024][512]
    bf16_t* __restrict__ C)          // [4096][1024]
{
    __shared__ bf16_t S[4 * 64 * 32];          // 16 KB total
    bf16_t* As0 = S;
    bf16_t* As1 = S + 2048;
    bf16_t* Bs0 = S + 4096;
    bf16_t* Bs1 = S + 6144;

    const int tid  = threadIdx.x;
    const int wave = tid >> 6;
    const int lane = tid & 63;
    const int l15  = lane & 15;
    const int quad = lane >> 4;
    const int bid  = blockIdx.x;
    const int m0   = (bid & 63) * 64;
    const int n0   = (bid >> 6) * 64;
    const int wm   = (wave >> 1) * 32;
    const int wn_  = (wave & 1) * 32;

    const int srow = lane >> 2;          // 0..15
    const int scol = (lane & 3) * 8;     // 0,8,16,24

    const bf16_t* agp = A  + (size_t)(m0 + wave * 16 + srow) * DIM + scol;
    const bf16_t* bgp = Bt + (size_t)(n0 + wave * 16 + srow) * DIM + scol;
    bf16_t* al0 = As0 + wave * 16 * 32;
    bf16_t* al1 = As1 + wave * 16 * 32;
    bf16_t* bl0 = Bs0 + wave * 16 * 32;
    bf16_t* bl1 = Bs1 + wave * 16 * 32;

    f32x4 acc[2][2] = {};

    for (int k0 = 0; k0 < DIM; k0 += 64) {
        __builtin_amdgcn_global_load_lds((gbl_cvoid*)(agp + k0),      (lds_void*)al0, 16, 0, 0);
        __builtin_amdgcn_global_load_lds((gbl_cvoid*)(agp + k0 + 32), (lds_void*)al1, 16, 0, 0);
        __builtin_amdgcn_global_load_lds((gbl_cvoid*)(bgp + k0),      (lds_void*)bl0, 16, 0, 0);
        __builtin_amdgcn_global_load_lds((gbl_cvoid*)(bgp + k0 + 32), (lds_void*)bl1, 16, 0, 0);
        __syncthreads();

        #pragma unroll
        for (int s = 0; s < 2; ++s) {
            const bf16_t* PA = s ? As1 : As0;
            const bf16_t* PB = s ? Bs1 : Bs0;
            bf16x8 af[2], bfv[2];
            #pragma unroll
            for (int mi = 0; mi < 2; ++mi)
                af[mi] = *(const bf16x8*)(PA + (wm + mi * 16 + l15) * 32 + quad * 8);
            #pragma unroll
            for (int ni = 0; ni < 2; ++ni)
                bfv[ni] = *(const bf16x8*)(PB + (wn_ + ni * 16 + l15) * 32 + quad * 8);
            #pragma unroll
            for (int mi = 0; mi < 2; ++mi)
                #pragma unroll
                for (int ni = 0; ni < 2; ++ni)
                    acc[mi][ni] = __builtin_amdgcn_mfma_f32_16x16x32_bf16(
                        af[mi], bfv[ni], acc[mi][ni], 0, 0, 0);
        }
        __syncthreads();
    }

    // ---- epilogue: repack 64x64 bf16 tile through LDS, uint4 stores ----
    bf16_t* Ct = S;   // 64 rows x 64 cols, stride 64 (8 KB)
    #pragma unroll
    for (int mi = 0; mi < 2; ++mi)
        #pragma unroll
        for (int ni = 0; ni < 2; ++ni)
            #pragma unroll
            for (int r = 0; r < 4; ++r)
                Ct[(wm + mi * 16 + quad * 4 + r) * 64 + wn_ + ni * 16 + l15] =
                    (bf16_t)acc[mi][ni][r];
    __syncthreads();
    #pragma unroll
    for (int i = 0; i < 4; ++i) {
        const int idx = i * 256 + tid;       // 0..1023
        const int row = idx >> 3;            // 0..127? -> 0..127 no: 1024/8=128
        const int c8  = idx & 7;
        if (row < 64)
            *(uint4*)(C + (size_t)(m0 + row) * 1024 + n0 + c8 * 8) =
                *(const uint4*)(Ct + row * 64 + c8 * 8);
    }
}

// ---------------------------------------------------------------------------
// Kernel 2: scores + softmax -> normalized weights wn_g[B*256][64][16].
// ---------------------------------------------------------------------------
#define QS 520

__global__ __launch_bounds__(256) void scores_k(
    const bf16_t* __restrict__ qkb,   // [4096][1024]  (q | k)
    float* __restrict__ wn_g)         // [B*256][64][16]
{
    __shared__ bf16_t Qb[16 * QS];
    __shared__ bf16_t Kb[32 * QS];
    __shared__ float sw2[NH][TI][24];

    const int tid  = threadIdx.x;
    const int wave = tid >> 6;
    const int lane = tid & 63;
    const int l15  = lane & 15;
    const int quad = lane >> 4;
    const int i0   = blockIdx.x * TI;
    const int b    = blockIdx.y;

    for (int r = wave; r < TI; r += 4) {
        const bf16_t* g = qkb + (size_t)(b * SEQ + i0 + r) * 1024 + lane * 8;
        __builtin_amdgcn_global_load_lds((gbl_cvoid*)g, (lds_void*)(Qb + r * QS), 16, 0, 0);
    }
    for (int r = wave; r < NROW; r += 4) {
        int jg = i0 - LR + r;
        jg = jg < 0 ? 0 : (jg > SEQ - 1 ? SEQ - 1 : jg);
        const bf16_t* g = qkb + (size_t)(b * SEQ + jg) * 1024 + DIM + lane * 8;
        __builtin_amdgcn_global_load_lds((gbl_cvoid*)g, (lds_void*)(Kb + r * QS), 16, 0, 0);
    }
    __syncthreads();

    #pragma unroll
    for (int hh = 0; hh < 2; ++hh) {
        const int h = wave * 2 + hh;
        f32x4 sacc[2] = {};
        #pragma unroll
        for (int s = 0; s < 2; ++s) {
            const bf16x8 aq = *(const bf16x8*)(Qb + l15 * QS + h * DH + s * 32 + quad * 8);
            #pragma unroll
            for (int t = 0; t < 2; ++t) {
                const bf16x8 bk = *(const bf16x8*)(Kb + (t * 16 + l15) * QS + h * DH + s * 32 + quad * 8);
                sacc[t] = __builtin_amdgcn_mfma_f32_16x16x32_bf16(aq, bk, sacc[t], 0, 0, 0);
            }
        }
        #pragma unroll
        for (int t = 0; t < 2; ++t) {
            const int jj = t * 16 + l15;
            if (jj < NROW) {
                #pragma unroll
                for (int r = 0; r < 4; ++r) {
                    const int ii = quad * 4 + r;
                    if (ii < TI) sw2[h][ii][jj] = sacc[t][r] * 0.125f;
                }
            }
        }
    }
    __syncthreads();

    if (tid < NH * TI) {
        const int h  = tid >> 3;
        const int ii = tid & (TI - 1);
        const int i  = i0 + ii;
        float v[16], m = -1e30f;
        #pragma unroll
        for (int t = 0; t < 15; ++t) {
            const int jg = i - LR + t;
            v[t] = (jg >= 0 && jg < SEQ) ? sw2[h][ii][ii + t] : -1e30f;
            m = fmaxf(m, v[t]);
        }
        float sum = 0.f;
        #pragma unroll
        for (int t = 0; t < 15; ++t) { v[t] = __expf(v[t] - m); sum += v[t]; }
        const float inv = 1.f / sum;
        #pragma unroll
        for (int t = 0; t < 15; ++t) v[t] *= inv;
        v[15] = 0.f;
        float* dst = wn_g + ((size_t)(b * 256 + blockIdx.x) * 64 + tid) * 16;
        #pragma unroll
        for (int u = 0; u < 4; ++u)
            *(float4*)(dst + u * 4) = make_float4(v[u*4], v[u*4+1], v[u*4+2], v[u*4+3]);
    }
}

// ---------------------------------------------------------------------------
// Kernel 3: context.  Block = (i-tile, d-half, b).  27 KB LDS.
// ---------------------------------------------------------------------------
#define BST 260

__global__ __launch_bounds__(256) void context_k(
    const float* __restrict__ hs,     // [B,SEQ,DIM] fp32
    const float* __restrict__ wn_g,   // [B*256][64][16]
    float* __restrict__ out)          // [B,NH,SEQ,DIM]
{
    __shared__ float band[NROW * BST];
    __shared__ float wnl[64 * 16];

    const int tid  = threadIdx.x;
    const int wave = tid >> 6;
    const int lane = tid & 63;
    const int tile = blockIdx.x;
    const int dh_  = blockIdx.y;
    const int b    = blockIdx.z;
    const int i0   = tile * TI;

    for (int r = wave; r < NROW; r += 4) {
        int jg = i0 - LR + r;
        jg = jg < 0 ? 0 : (jg > SEQ - 1 ? SEQ - 1 : jg);
        const float* g = hs + ((size_t)b * SEQ + jg) * DIM + dh_ * 256 + lane * 4;
        __builtin_amdgcn_global_load_lds((gbl_cvoid*)g, (lds_void*)(band + r * BST), 16, 0, 0);
    }
    {
        const float* g = wn_g + (size_t)(b * 256 + tile) * 1024 + wave * 256 + lane * 4;
        __builtin_amdgcn_global_load_lds((gbl_cvoid*)g, (lds_void*)(wnl + wave * 256), 16, 0, 0);
    }
    __syncthreads();

    const int h  = tid >> 5;
    const int iq = (tid >> 4) & 1;
    const int dg = tid & 15;

    float wreg[4][15];
    #pragma unroll
    for (int t = 0; t < 4; ++t) {
        const int pair = h * TI + iq * 4 + t;
        #pragma unroll
        for (int j = 0; j < 15; ++j) wreg[t][j] = wnl[pair * 16 + j];
    }

    const int r0 = iq * 4;
    float* op = out + ((size_t)(b * NH + h) * SEQ + i0 + iq * 4) * DIM + dh_ * 256;

    for (int c = 0; c < 4; ++c) {
        const int dbase = c * 64 + dg * 4;
        float4 a0 = {0,0,0,0}, a1 = {0,0,0,0}, a2 = {0,0,0,0}, a3 = {0,0,0,0};
        #pragma unroll
        for (int rr = 0; rr < 18; ++rr) {
            const float4 v = *(const float4*)&band[(r0 + rr) * BST + dbase];
            if (rr <= 14) {
                const float w = wreg[0][rr];
                a0.x += w * v.x; a0.y += w * v.y; a0.z += w * v.z; a0.w += w * v.w;
            }
            if (rr >= 1 && rr <= 15) {
                const float w = wreg[1][rr - 1];
                a1.x += w * v.x; a1.y += w * v.y; a1.z += w * v.z; a1.w += w * v.w;
            }
            if (rr >= 2 && rr <= 16) {
                const float w = wreg[2][rr - 2];
                a2.x += w * v.x; a2.y += w * v.y; a2.z += w * v.z; a2.w += w * v.w;
            }
            if (rr >= 3) {
                const float w = wreg[3][rr - 3];
                a3.x += w * v.x; a3.y += w * v.y; a3.z += w * v.z; a3.w += w * v.w;
            }
        }
        *(float4*)(op + (size_t)0 * DIM + dbase) = a0;
        *(float4*)(op + (size_t)1 * DIM + dbase) = a1;
        *(float4*)(op + (size_t)2 * DIM + dbase) = a2;
        *(float4*)(op + (size_t)3 * DIM + dbase) = a3;
    }
}

// ---------------------------------------------------------------------------
extern "C" void kernel_launch(void* const* d_in, const int* in_sizes, int n_in,
                              void* d_out, int out_size, void* d_ws, size_t ws_size,
                              hipStream_t stream)
{
    const float* hs = (const float*)d_in[0];
    const float* Wq = (const float*)d_in[1];
    const float* Wk = (const float*)d_in[2];
    float* out = (float*)d_out;

    const int B = in_sizes[0] / (SEQ * DIM);   // 2
    const int M = B * SEQ;                     // 4096

    bf16_t* hsb  = (bf16_t*)d_ws;                          // 4 MB
    bf16_t* Wt   = (bf16_t*)((char*)d_ws + (4 << 20));     // 1 MB
    bf16_t* qkb  = (bf16_t*)((char*)d_ws + (5 << 20));     // 8 MB
    float*  wn_g = (float*)((char*)d_ws + (13 << 20));     // 2 MB

    prep<<<1024 + 128, 256, 0, stream>>>(hs, Wq, Wk, hsb, Wt);
    qk_gemm_v6<<<(M / 64) * (1024 / 64), 256, 0, stream>>>(hsb, Wt, qkb);
    scores_k<<<dim3(SEQ / TI, B), 256, 0, stream>>>(qkb, wn_g);
    context_k<<<dim3(SEQ / TI, 2, B), 256, 0, stream>>>(hs, wn_g, out);
}